// Round 3
// baseline (76.469 us; speedup 1.0000x reference)
//
#include <hip/hip_runtime.h>

// BatchedLUTNodes: out[b,n] = 6-D multilinear interpolation of tables[n,0..63]
// at coords x[b,n,0..5] clipped to [0,1]. 63 lerps/output == reference's
// weight-product + dot (verified R1, absmax 3.9e-3 << 1.8e-2 threshold).
//
// R3 change vs R2: drop LDS entirely. Each thread loads its own node's
// 64-entry table row directly into registers (16x global_load_dwordx4,
// 256 B/lane stride). No intra-block sharing exists (one node per thread);
// cross-block table reuse is served by L1 (16 KB tile per block's 4 waves)
// and L2 (2 MB table < 4 MB/XCD). Removes ~1300 LDS wave-instrs/CU and the
// __syncthreads serialization of R2.

#define THREADS 256
#define NPB 64   // nodes per block
#define BPB 16   // batches per block (4 per thread)

__global__ __launch_bounds__(THREADS)
void lut_fold_kernel(const float* __restrict__ x,
                     const float* __restrict__ tables,
                     float* __restrict__ out) {
    const int tid       = threadIdx.x;
    const int node_tile = blockIdx.x & 127;   // 128 node tiles
    const int bgroup    = blockIdx.x >> 7;    // 0..7 batch groups
    const int n_local   = tid & 63;
    const int n         = node_tile * NPB + n_local;
    const int bbase     = bgroup * BPB + (tid >> 6) * (BPB / 4);

    // ---- This node's table row straight into registers ----
    float t[64];
    {
        const float4* tr = (const float4*)(tables + (long)n * 64);
        #pragma unroll
        for (int k = 0; k < 16; ++k) {
            const float4 v = tr[k];           // lanes stride 256 B; L1-friendly
            t[4*k+0] = v.x; t[4*k+1] = v.y; t[4*k+2] = v.z; t[4*k+3] = v.w;
        }
    }

    // ---- 4 batches per thread ----
    #pragma unroll
    for (int bl = 0; bl < BPB / 4; ++bl) {
        const int b = bbase + bl;

        // x[b][n][0..5]: lanes are consecutive n -> contiguous 24 B/lane.
        const float2* xp = (const float2*)(x + ((long)b * 8192 + n) * 6);
        const float2 p0 = xp[0];
        const float2 p1 = xp[1];
        const float2 p2 = xp[2];
        const float x0 = fminf(fmaxf(p0.x, 0.f), 1.f);
        const float x1 = fminf(fmaxf(p0.y, 0.f), 1.f);
        const float x2 = fminf(fmaxf(p1.x, 0.f), 1.f);
        const float x3 = fminf(fmaxf(p1.y, 0.f), 1.f);
        const float x4 = fminf(fmaxf(p2.x, 0.f), 1.f);
        const float x5 = fminf(fmaxf(p2.y, 0.f), 1.f);

        // ---- 6-level fold: lerp(lo,hi,xi) = fma(xi, hi-lo, lo) ----
        float a[32];
        #pragma unroll
        for (int j = 0; j < 32; ++j) a[j] = fmaf(x0, t[2*j+1] - t[2*j], t[2*j]);
        #pragma unroll
        for (int j = 0; j < 16; ++j) a[j] = fmaf(x1, a[2*j+1] - a[2*j], a[2*j]);
        #pragma unroll
        for (int j = 0; j < 8;  ++j) a[j] = fmaf(x2, a[2*j+1] - a[2*j], a[2*j]);
        #pragma unroll
        for (int j = 0; j < 4;  ++j) a[j] = fmaf(x3, a[2*j+1] - a[2*j], a[2*j]);
        #pragma unroll
        for (int j = 0; j < 2;  ++j) a[j] = fmaf(x4, a[2*j+1] - a[2*j], a[2*j]);
        const float r = fmaf(x5, a[1] - a[0], a[0]);

        out[(long)b * 8192 + n] = r;   // coalesced 4 B/lane
    }
}

extern "C" void kernel_launch(void* const* d_in, const int* in_sizes, int n_in,
                              void* d_out, int out_size, void* d_ws, size_t ws_size,
                              hipStream_t stream) {
    const float* x      = (const float*)d_in[0];   // 128*8192*6 f32
    const float* tables = (const float*)d_in[1];   // 8192*64 f32
    float* out          = (float*)d_out;           // 128*8192 f32

    dim3 grid(1024);  // 128 node tiles x 8 batch groups
    dim3 block(THREADS);
    hipLaunchKernelGGL(lut_fold_kernel, grid, block, 0, stream, x, tables, out);
}

// Round 4
// 71.252 us; speedup vs baseline: 1.0732x; 1.0732x over previous
//
#include <hip/hip_runtime.h>

// BatchedLUTNodes: out[b,n] = 6-D multilinear interpolation of tables[n,0..63]
// at coords x[b,n,0..5] clipped to [0,1]. 63 lerps/output == reference's
// weight-product + dot (verified R1-R3, absmax 3.9e-3 << 1.8e-2 threshold).
//
// R4 vs R2 (best so far; R3's no-LDS direct loads regressed +6us -- 64
// cachelines/instr on the strided table reads):
//  1. Issue order: staging dwordx4 FIRST, then 12 x float2 loads, then LDS
//     writes. vmcnt counts oldest-first, so ds_write waits vmcnt(12) -- the
//     x loads stay in flight across the barrier + t-fill (~900 cyc overlap).
//  2. Table kept as (lo, delta) register pairs: level-1 deltas are
//     batch-invariant, saves 96 VALU instrs/thread. Same 64 VGPRs.
//
// LDS: rows padded to 65 floats; register-fill (lane=row r, scan e):
// bank=(r+e)%32 -> 2 lanes/bank = free (m136).

#define THREADS 256
#define NPB 64   // nodes per block
#define BPB 16   // batches per block (4 per thread)
#define PAD 65   // padded LDS row length

__global__ __launch_bounds__(THREADS)
void lut_fold_kernel(const float* __restrict__ x,
                     const float* __restrict__ tables,
                     float* __restrict__ out) {
    __shared__ float lt[NPB * PAD];

    const int tid       = threadIdx.x;
    const int node_tile = blockIdx.x & 127;   // 128 node tiles
    const int bgroup    = blockIdx.x >> 7;    // 0..7 batch groups
    const int node0     = node_tile * NPB;
    const int n_local   = tid & 63;
    const int n         = node0 + n_local;
    const int bbase     = bgroup * BPB + (tid >> 6) * (BPB / 4);

    // ---- (1) staging loads first (oldest in vmcnt queue) ----
    float4 stage[4];
    {
        const float4* gt4 = (const float4*)(tables + (long)node0 * 64);
        #pragma unroll
        for (int k = 0; k < 4; ++k)
            stage[k] = gt4[tid + THREADS * k];    // coalesced 16 B/lane
    }

    // ---- (2) x loads issued now; stay in flight across barrier ----
    float2 p[4][3];
    #pragma unroll
    for (int bl = 0; bl < 4; ++bl) {
        const float2* xp = (const float2*)(x + ((long)(bbase + bl) * 8192 + n) * 6);
        p[bl][0] = xp[0];
        p[bl][1] = xp[1];
        p[bl][2] = xp[2];
    }

    // ---- (3) LDS writes (wait only on the 4 staging loads) ----
    #pragma unroll
    for (int k = 0; k < 4; ++k) {
        const int g4  = tid + THREADS * k;        // float4 index 0..1023
        const int row = g4 >> 4;
        const int col = (g4 & 15) * 4;
        float* d = &lt[row * PAD + col];
        d[0] = stage[k].x; d[1] = stage[k].y; d[2] = stage[k].z; d[3] = stage[k].w;
    }
    __syncthreads();

    // ---- (4) table row -> registers as (lo, delta) pairs ----
    float tlo[32], td[32];
    #pragma unroll
    for (int e = 0; e < 32; ++e) {
        const float lo = lt[n_local * PAD + 2 * e];
        const float hi = lt[n_local * PAD + 2 * e + 1];
        tlo[e] = lo;
        td[e]  = hi - lo;
    }

    // ---- (5) 4 independent 6-level folds ----
    #pragma unroll
    for (int bl = 0; bl < 4; ++bl) {
        const float x0 = fminf(fmaxf(p[bl][0].x, 0.f), 1.f);
        const float x1 = fminf(fmaxf(p[bl][0].y, 0.f), 1.f);
        const float x2 = fminf(fmaxf(p[bl][1].x, 0.f), 1.f);
        const float x3 = fminf(fmaxf(p[bl][1].y, 0.f), 1.f);
        const float x4 = fminf(fmaxf(p[bl][2].x, 0.f), 1.f);
        const float x5 = fminf(fmaxf(p[bl][2].y, 0.f), 1.f);

        float a[32];
        #pragma unroll
        for (int j = 0; j < 32; ++j) a[j] = fmaf(x0, td[j], tlo[j]);
        #pragma unroll
        for (int j = 0; j < 16; ++j) a[j] = fmaf(x1, a[2*j+1] - a[2*j], a[2*j]);
        #pragma unroll
        for (int j = 0; j < 8;  ++j) a[j] = fmaf(x2, a[2*j+1] - a[2*j], a[2*j]);
        #pragma unroll
        for (int j = 0; j < 4;  ++j) a[j] = fmaf(x3, a[2*j+1] - a[2*j], a[2*j]);
        #pragma unroll
        for (int j = 0; j < 2;  ++j) a[j] = fmaf(x4, a[2*j+1] - a[2*j], a[2*j]);
        const float r = fmaf(x5, a[1] - a[0], a[0]);

        out[(long)(bbase + bl) * 8192 + n] = r;   // coalesced 4 B/lane
    }
}

extern "C" void kernel_launch(void* const* d_in, const int* in_sizes, int n_in,
                              void* d_out, int out_size, void* d_ws, size_t ws_size,
                              hipStream_t stream) {
    const float* x      = (const float*)d_in[0];   // 128*8192*6 f32
    const float* tables = (const float*)d_in[1];   // 8192*64 f32
    float* out          = (float*)d_out;           // 128*8192 f32

    dim3 grid(1024);  // 128 node tiles x 8 batch groups
    dim3 block(THREADS);
    hipLaunchKernelGGL(lut_fold_kernel, grid, block, 0, stream, x, tables, out);
}